// Round 7
// baseline (498.705 us; speedup 1.0000x reference)
//
#include <hip/hip_runtime.h>
#include <hip/hip_cooperative_groups.h>
#include <math.h>

namespace cg = cooperative_groups;

#define CDIM 1024
#define TC   3072
#define NIN  2048   // input rows per batch (class token handled separately)

// ---------------- fused-kernel workspace offsets (floats) ----------------
#define F_Q0P 0           // 16*1024 q0 i-chunk partials
#define F_WS  16384       // 4*1024  [h][c]
#define F_PS  20480       // 256*4   per-block exp-sums
#define F_PY  21504       // 256*4096 per-block y partials (PERMUTED layout)
#define F_YB  1070080     // 8*4*1024 attention-averaged rows (natural layout)
#define F_OCP 1102848     // 16(q)*8(b)*1024 oc partials

// permuted ybuf layout: slot(h, c) with c = k*256 + l*4 + j (l=lane, j=0..3)
//   -> h*1024 + k*256 + j*64 + l   (stride-1 across lanes per (k,j) instr)

__global__ __launch_bounds__(1024, 4) void k_fused(
    const float* __restrict__ x, const float* __restrict__ t,
    const float* __restrict__ Wqkv, const float* __restrict__ bqkv,
    const float* __restrict__ Wv, const float* __restrict__ bv,
    float* __restrict__ wsb, float* __restrict__ out)
{
    cg::grid_group grid = cg::this_grid();
    __shared__ float ybuf[4 * CDIM];   // 16 KB; reused: P2 q0full, P3 merge, P5/P6 staging
    __shared__ float ps[4];
    __shared__ float red[16];
    int tid = threadIdx.x, lane = tid & 63, wave = tid >> 6;
    int blk = blockIdx.x;

    // ---- P1: q0 partials (blocks 0..63) + zero out (block 64) ----
    if (blk < 64) {
        if (tid < 256) {
            int ic = blk >> 2, jc = blk & 3;       // 16 i-chunks of 64, 4 j-chunks of 256
            int j = jc * 256 + tid;
            int i0 = ic * 64;
            float acc = 0.f;
            for (int i = 0; i < 64; ++i)
                acc += t[i0 + i] * Wqkv[(size_t)(i0 + i) * TC + j];
            wsb[F_Q0P + ic * CDIM + j] = acc;
        }
    } else if (blk == 64) {
        for (int r = 0; r < 8; ++r) out[r * 1024 + tid] = 0.f;
    }
    grid.sync();

    // ---- P2: q0full in LDS, then Ws[h][c] (all 256 blocks; 16 (c,h) dots each) ----
    if (tid < 256) {
        float4 q = *(const float4*)&bqkv[tid * 4];
#pragma unroll
        for (int ic = 0; ic < 16; ++ic) {
            float4 p = *(const float4*)&wsb[F_Q0P + ic * CDIM + tid * 4];
            q.x += p.x; q.y += p.y; q.z += p.z; q.w += p.w;
        }
        *(float4*)&ybuf[tid * 4] = q;
    }
    __syncthreads();
    {
        int c = blk * 4 + (wave >> 2), h = wave & 3;
        int d0 = h * 256 + lane * 4;
        float4 wv = *(const float4*)&Wqkv[(size_t)c * TC + CDIM + d0];
        float4 qv = *(const float4*)&ybuf[d0];
        float a = wv.x * qv.x + wv.y * qv.y + wv.z * qv.z + wv.w * qv.w;
        for (int off = 32; off > 0; off >>= 1) a += __shfl_down(a, off);
        if (lane == 0) wsb[F_WS + h * CDIM + c] = a;
    }
    grid.sync();

    // ---- P3: X scan — exp(score) + weighted row-sum; LDS-atomic block merge ----
    {
        float4 wsr[4][4];
#pragma unroll
        for (int k = 0; k < 4; ++k)
#pragma unroll
            for (int h = 0; h < 4; ++h)
                wsr[k][h] = *(const float4*)&wsb[F_WS + h * CDIM + k * 256 + lane * 4];
        float s[4] = {0.f, 0.f, 0.f, 0.f};
        float4 y[4][4];
#pragma unroll
        for (int h = 0; h < 4; ++h)
#pragma unroll
            for (int k = 0; k < 4; ++k) y[h][k] = make_float4(0.f, 0.f, 0.f, 0.f);

        int b = blk >> 5, ch = blk & 31;
        const float* base = x + ((size_t)b * NIN + ch * 64 + wave * 4) * CDIM;
#pragma unroll 2
        for (int i = 0; i < 4; ++i) {
            const float* row = base + (size_t)i * CDIM;
            float4 xv[4];
#pragma unroll
            for (int k = 0; k < 4; ++k) xv[k] = *(const float4*)&row[k * 256 + lane * 4];
            float e[4];
#pragma unroll
            for (int h = 0; h < 4; ++h) {
                float a = 0.f;
#pragma unroll
                for (int k = 0; k < 4; ++k)
                    a += xv[k].x * wsr[k][h].x + xv[k].y * wsr[k][h].y +
                         xv[k].z * wsr[k][h].z + xv[k].w * wsr[k][h].w;
                for (int off = 1; off < 64; off <<= 1) a += __shfl_xor(a, off);
                e[h] = __expf(a * 0.0625f);   // Dh=256 -> 1/16; +ck cancels in softmax
            }
#pragma unroll
            for (int h = 0; h < 4; ++h) {
                float f = e[h];
                s[h] += f;
#pragma unroll
                for (int k = 0; k < 4; ++k) {
                    y[h][k].x += f * xv[k].x; y[h][k].y += f * xv[k].y;
                    y[h][k].z += f * xv[k].z; y[h][k].w += f * xv[k].w;
                }
            }
        }
        __syncthreads();                       // ybuf done serving P2
        *(float4*)&ybuf[tid * 4] = make_float4(0.f, 0.f, 0.f, 0.f);
        if (tid < 4) ps[tid] = 0.f;
        __syncthreads();
#pragma unroll
        for (int h = 0; h < 4; ++h)
#pragma unroll
            for (int k = 0; k < 4; ++k) {
                float* bp = &ybuf[h * 1024 + k * 256];
                atomicAdd(&bp[0 * 64 + lane], y[h][k].x);
                atomicAdd(&bp[1 * 64 + lane], y[h][k].y);
                atomicAdd(&bp[2 * 64 + lane], y[h][k].z);
                atomicAdd(&bp[3 * 64 + lane], y[h][k].w);
            }
        if (lane == 0)
#pragma unroll
            for (int h = 0; h < 4; ++h) atomicAdd(&ps[h], s[h]);
        __syncthreads();
        *(float4*)&wsb[F_PY + (size_t)blk * 4096 + tid * 4] = *(const float4*)&ybuf[tid * 4];
        if (tid < 4) wsb[F_PS + blk * 4 + tid] = ps[tid];
    }
    grid.sync();

    // ---- P4: combine 32 block-partials + class-token term -> ybar (128 roles) ----
    if (blk < 128) {
        int b = blk >> 4, h = (blk >> 2) & 3, kq = blk & 3;
        // sc0 = (t . Ws_h)/16  (batch-independent)
        if (tid < 256) {
            float4 tv = *(const float4*)&t[tid * 4];
            float4 wsv = *(const float4*)&wsb[F_WS + h * CDIM + tid * 4];
            float p = tv.x * wsv.x + tv.y * wsv.y + tv.z * wsv.z + tv.w * wsv.w;
            for (int off = 1; off < 64; off <<= 1) p += __shfl_xor(p, off);
            if (lane == 0) red[wave] = p;
        }
        if (wave == 0) {
            float sv = (lane < 32) ? wsb[F_PS + (size_t)(b * 32 + lane) * 4 + h] : 0.f;
            for (int off = 32; off > 0; off >>= 1) sv += __shfl_down(sv, off);
            if (lane == 0) red[8] = sv;
        }
        __syncthreads();
        float sc0 = (red[0] + red[1] + red[2] + red[3]) * 0.0625f;
        float e0 = __expf(sc0);
        float S = red[8] + e0;
        if (tid < 256) {
            int pidx = h * 1024 + kq * 256 + tid;          // permuted slot
            int c = kq * 256 + (tid & 63) * 4 + (tid >> 6); // natural column
            float acc = 0.f;
#pragma unroll 4
            for (int m = 0; m < 32; ++m)
                acc += wsb[F_PY + (size_t)(b * 32 + m) * 4096 + pidx];
            wsb[F_YB + (size_t)(b * 4 + h) * CDIM + c] = (acc + e0 * t[c]) / S;
        }
    }
    grid.sync();

    // ---- P5: oc partials: ocp[q][b][cp] = ybar[b][h(cp)][q-chunk] . Wv_qkv (128 roles) ----
    if (blk < 128) {
        int p = blk >> 4, q = blk & 15;       // p: cp-chunk of 128; q: c-chunk of 64
        int h = p >> 1;
        if (tid < 512) {
            int bb = tid >> 6, cc = tid & 63;
            ybuf[tid] = wsb[F_YB + (size_t)(bb * 4 + h) * CDIM + q * 64 + cc];
        }
        __syncthreads();
        int bb = tid >> 7, cl = tid & 127;
        int cp = p * 128 + cl;
        float acc = 0.f;
#pragma unroll 8
        for (int c = 0; c < 64; ++c)
            acc += ybuf[bb * 64 + c] * Wqkv[(size_t)(q * 64 + c) * TC + 2 * CDIM + cp];
        if (q == 0) acc += bqkv[2 * CDIM + cp];
        wsb[F_OCP + (size_t)(q * 8 + bb) * CDIM + cp] = acc;
        __syncthreads();                       // ybuf reuse safety before P6
    }
    grid.sync();

    // ---- P6: out[b][j] = oc[b] . Wv[:, j] + bv (128 roles, atomic into zeroed out) ----
    if (blk < 128) {
        int jp = blk >> 4, cq = blk & 15;     // jp: j-chunk of 128; cq: c-chunk of 64
        if (tid < 512) {
            int bb = tid >> 6, cc = tid & 63;
            float sum = 0.f;
#pragma unroll
            for (int q = 0; q < 16; ++q)
                sum += wsb[F_OCP + (size_t)(q * 8 + bb) * CDIM + cq * 64 + cc];
            ybuf[tid] = sum;
        }
        __syncthreads();
        int bb = tid >> 7, jl = tid & 127;
        int j = jp * 128 + jl;
        float acc = 0.f;
#pragma unroll 8
        for (int c = 0; c < 64; ++c)
            acc += ybuf[bb * 64 + c] * Wv[(size_t)(cq * 64 + c) * CDIM + j];
        if (cq == 0) acc += bv[j];
        atomicAdd(&out[bb * CDIM + j], acc);
    }
}

// ================= fallback: R6 stream-ordered pipeline =================
#define OFF_Q0P 0
#define OFF_WS  16384
#define OFF_PS2 20480
#define OFF_PY2 24576
#define OFF_YB2 4218880
#define OFF_OCP2 4251648

__global__ void k_q0(const float* __restrict__ t, const float* __restrict__ W,
                     float* __restrict__ wsb) {
    int ic = blockIdx.x >> 3, jc = blockIdx.x & 7;
    int j = jc * 128 + threadIdx.x;
    int i0 = ic * 64;
    float acc = 0.f;
    for (int i = 0; i < 64; ++i)
        acc += t[i0 + i] * W[(size_t)(i0 + i) * TC + j];
    wsb[OFF_Q0P + ic * CDIM + j] = acc;
}

__global__ void k_ws(const float* __restrict__ W, const float* __restrict__ bqkv,
                     float* __restrict__ wsb) {
    int wave = threadIdx.x >> 6, lane = threadIdx.x & 63;
    int c = blockIdx.x, h = wave;
    int d0 = h * 256 + lane * 4;
    float4 wv = *(const float4*)&W[(size_t)c * TC + CDIM + d0];
    float4 q = *(const float4*)&bqkv[d0];
#pragma unroll
    for (int ic = 0; ic < 16; ++ic) {
        float4 p = *(const float4*)&wsb[OFF_Q0P + ic * CDIM + d0];
        q.x += p.x; q.y += p.y; q.z += p.z; q.w += p.w;
    }
    float acc = wv.x * q.x + wv.y * q.y + wv.z * q.z + wv.w * q.w;
    for (int off = 32; off > 0; off >>= 1) acc += __shfl_down(acc, off);
    if (lane == 0) wsb[OFF_WS + h * CDIM + c] = acc;
}

__global__ __launch_bounds__(256) void k_pass1(const float* __restrict__ x,
                                               float* __restrict__ wsb) {
    int tid = threadIdx.x, lane = tid & 63, wave = tid >> 6;
    int b = blockIdx.x >> 7, blkc = blockIdx.x & 127;
    float4 wsr[4][4];
#pragma unroll
    for (int k = 0; k < 4; ++k)
#pragma unroll
        for (int h = 0; h < 4; ++h)
            wsr[k][h] = *(const float4*)&wsb[OFF_WS + h * CDIM + k * 256 + lane * 4];
    float s[4] = {0.f, 0.f, 0.f, 0.f};
    float4 y[4][4];
#pragma unroll
    for (int h = 0; h < 4; ++h)
#pragma unroll
        for (int k = 0; k < 4; ++k) y[h][k] = make_float4(0.f, 0.f, 0.f, 0.f);
    const float* base = x + ((size_t)b * NIN + blkc * 16 + wave * 4) * CDIM;
#pragma unroll 2
    for (int i = 0; i < 4; ++i) {
        const float* row = base + (size_t)i * CDIM;
        float4 xv[4];
#pragma unroll
        for (int k = 0; k < 4; ++k) xv[k] = *(const float4*)&row[k * 256 + lane * 4];
        float e[4];
#pragma unroll
        for (int h = 0; h < 4; ++h) {
            float a = 0.f;
#pragma unroll
            for (int k = 0; k < 4; ++k)
                a += xv[k].x * wsr[k][h].x + xv[k].y * wsr[k][h].y +
                     xv[k].z * wsr[k][h].z + xv[k].w * wsr[k][h].w;
            for (int off = 1; off < 64; off <<= 1) a += __shfl_xor(a, off);
            e[h] = __expf(a * 0.0625f);
        }
#pragma unroll
        for (int h = 0; h < 4; ++h) {
            float f = e[h];
            s[h] += f;
#pragma unroll
            for (int k = 0; k < 4; ++k) {
                y[h][k].x += f * xv[k].x; y[h][k].y += f * xv[k].y;
                y[h][k].z += f * xv[k].z; y[h][k].w += f * xv[k].w;
            }
        }
    }
    __shared__ float ss[4][4];
    __shared__ float ybuf[4][CDIM];
    if (lane == 0)
#pragma unroll
        for (int h = 0; h < 4; ++h) ss[wave][h] = s[h];
    for (int idx = tid; idx < 4 * CDIM; idx += 256) ((float*)ybuf)[idx] = 0.f;
    __syncthreads();
    for (int w = 0; w < 4; ++w) {
        if (wave == w) {
#pragma unroll
            for (int h = 0; h < 4; ++h)
#pragma unroll
                for (int k = 0; k < 4; ++k) {
                    float4* dst = (float4*)&ybuf[h][k * 256 + lane * 4];
                    float4 v = *dst;
                    v.x += y[h][k].x; v.y += y[h][k].y;
                    v.z += y[h][k].z; v.w += y[h][k].w;
                    *dst = v;
                }
        }
        __syncthreads();
    }
    int p = blockIdx.x;
    if (tid < 4)
        wsb[OFF_PS2 + p * 4 + tid] = ss[0][tid] + ss[1][tid] + ss[2][tid] + ss[3][tid];
    for (int idx = tid; idx < 4 * CDIM; idx += 256)
        wsb[OFF_PY2 + (size_t)p * 4096 + idx] = ((float*)ybuf)[idx];
}

__global__ void k_comb(const float* __restrict__ t, float* __restrict__ wsb) {
    int tid = threadIdx.x, lane = tid & 63, wv = tid >> 6;
    int blk = blockIdx.x;
    int b = blk >> 4, h = (blk >> 2) & 3, cq = blk & 3;
    __shared__ float red[4], redS[4];
    int c0 = tid * 4;
    float4 tv = *(const float4*)&t[c0];
    float4 wsv = *(const float4*)&wsb[OFF_WS + h * CDIM + c0];
    float p = tv.x * wsv.x + tv.y * wsv.y + tv.z * wsv.z + tv.w * wsv.w;
    for (int off = 1; off < 64; off <<= 1) p += __shfl_xor(p, off);
    if (lane == 0) red[wv] = p;
    float sv = (tid < 128) ? wsb[OFF_PS2 + (size_t)(b * 128 + tid) * 4 + h] : 0.f;
    for (int off = 1; off < 64; off <<= 1) sv += __shfl_xor(sv, off);
    if (lane == 0) redS[wv] = sv;
    __syncthreads();
    float sc0 = (red[0] + red[1] + red[2] + red[3]) * 0.0625f;
    float e0 = __expf(sc0);
    float S = redS[0] + redS[1] + redS[2] + redS[3] + e0;
    int c = cq * 256 + tid;
    float acc = e0 * t[c];
#pragma unroll 4
    for (int j = 0; j < 128; ++j)
        acc += wsb[OFF_PY2 + (size_t)(b * 128 + j) * 4096 + h * CDIM + c];
    wsb[OFF_YB2 + (size_t)(b * 4 + h) * CDIM + c] = acc / S;
}

__global__ void k_ocy(const float* __restrict__ W, const float* __restrict__ bqkv,
                      float* __restrict__ wsb, float* __restrict__ out) {
    out[blockIdx.x * 128 + threadIdx.x] = 0.f;
    int p = blockIdx.x >> 3, q = blockIdx.x & 7;
    int h = p >> 1;
    __shared__ float sL[1024];
    for (int bb = 0; bb < 8; ++bb)
        sL[bb * 128 + threadIdx.x] = wsb[OFF_YB2 + (size_t)(bb * 4 + h) * CDIM + q * 128 + threadIdx.x];
    __syncthreads();
    int cp = p * 128 + threadIdx.x;
    float acc[8] = {0.f, 0.f, 0.f, 0.f, 0.f, 0.f, 0.f, 0.f};
    for (int c = 0; c < 128; ++c) {
        float wv = W[(size_t)(q * 128 + c) * TC + 2 * CDIM + cp];
#pragma unroll
        for (int bb = 0; bb < 8; ++bb) acc[bb] += sL[bb * 128 + c] * wv;
    }
    if (q == 0) {
        float bias = bqkv[2 * CDIM + cp];
#pragma unroll
        for (int bb = 0; bb < 8; ++bb) acc[bb] += bias;
    }
#pragma unroll
    for (int bb = 0; bb < 8; ++bb)
        wsb[OFF_OCP2 + (size_t)(q * 8 + bb) * CDIM + cp] = acc[bb];
}

__global__ void k_out(const float* __restrict__ Wv, const float* __restrict__ bv,
                      const float* __restrict__ wsb, float* __restrict__ out) {
    int jp = blockIdx.x >> 3, cq = blockIdx.x & 7;
    __shared__ float ocL[1024];
    for (int bb = 0; bb < 8; ++bb) {
        float sum = 0.f;
#pragma unroll
        for (int q = 0; q < 8; ++q)
            sum += wsb[OFF_OCP2 + (size_t)(q * 8 + bb) * CDIM + cq * 128 + threadIdx.x];
        ocL[bb * 128 + threadIdx.x] = sum;
    }
    __syncthreads();
    int j = jp * 128 + threadIdx.x;
    float acc[8] = {0.f, 0.f, 0.f, 0.f, 0.f, 0.f, 0.f, 0.f};
    for (int c = 0; c < 128; ++c) {
        float wv = Wv[(size_t)(cq * 128 + c) * CDIM + j];
#pragma unroll
        for (int bb = 0; bb < 8; ++bb) acc[bb] += ocL[bb * 128 + c] * wv;
    }
    if (cq == 0) {
        float bias = bv[j];
#pragma unroll
        for (int bb = 0; bb < 8; ++bb) acc[bb] += bias;
    }
#pragma unroll
    for (int bb = 0; bb < 8; ++bb) atomicAdd(&out[bb * CDIM + j], acc[bb]);
}

extern "C" void kernel_launch(void* const* d_in, const int* in_sizes, int n_in,
                              void* d_out, int out_size, void* d_ws, size_t ws_size,
                              hipStream_t stream) {
    const float* x    = (const float*)d_in[0];   // [8,2048,1024]
    const float* t    = (const float*)d_in[1];   // [1,1,1024]
    const float* Wqkv = (const float*)d_in[2];   // [1024,3072]
    const float* bqkv = (const float*)d_in[3];   // [3072]
    const float* Wv   = (const float*)d_in[4];   // [1024,1024]
    const float* bv   = (const float*)d_in[5];   // [1024]
    float* wsb = (float*)d_ws;
    float* out = (float*)d_out;                  // [8,1024] fp32

    void* args[] = {(void*)&x, (void*)&t, (void*)&Wqkv, (void*)&bqkv,
                    (void*)&Wv, (void*)&bv, (void*)&wsb, (void*)&out};
    hipError_t err = hipLaunchCooperativeKernel((void*)k_fused, dim3(256), dim3(1024),
                                                args, 0, stream);
    if (err != hipSuccess) {
        // deterministic fallback: R6 stream-ordered pipeline (179 us measured)
        k_q0   <<<128,  128, 0, stream>>>(t, Wqkv, wsb);
        k_ws   <<<1024, 256, 0, stream>>>(Wqkv, bqkv, wsb);
        k_pass1<<<1024, 256, 0, stream>>>(x, wsb);
        k_comb <<<128,  256, 0, stream>>>(t, wsb);
        k_ocy  <<<64,   128, 0, stream>>>(Wqkv, bqkv, wsb, out);
        k_out  <<<64,   128, 0, stream>>>(Wv, bv, wsb, out);
    }
}

// Round 8
// 366.814 us; speedup vs baseline: 1.3596x; 1.3596x over previous
//
#include <hip/hip_runtime.h>
#include <hip/hip_cooperative_groups.h>
#include <math.h>

namespace cg = cooperative_groups;

#define CDIM 1024
#define TC   3072
#define NIN  2048   // input rows per batch (class token handled separately)

// ---------------- fused-kernel workspace offsets (floats) ----------------
#define F_Q0P 0           // 16*1024 q0 i-chunk partials
#define F_WS  16384       // 4*1024  [h][c]
#define F_PS  20480       // 256*4   per-block exp-sums
#define F_PY  21504       // 256*4096 per-block y partials (PERMUTED layout)
#define F_YB  1070080     // 8*4*1024 attention-averaged rows (natural layout)
#define F_OCP 1102848     // 16(q)*8(b)*1024 oc partials

// permuted ybuf layout: slot(h, c) with c = k*256 + l*4 + j (l=lane, j=0..3)
//   -> h*1024 + k*256 + j*64 + l   (stride-1 across lanes per (k,j) instr)

// NOTE: plain __launch_bounds__(1024) -> VGPR cap 128 (R7's ",4" capped at 64
// and spilled: 233 MB WRITE_SIZE). P3 is two head-pair passes to stay ~95 VGPR.
__global__ __launch_bounds__(1024) void k_fused(
    const float* __restrict__ x, const float* __restrict__ t,
    const float* __restrict__ Wqkv, const float* __restrict__ bqkv,
    const float* __restrict__ Wv, const float* __restrict__ bv,
    float* __restrict__ wsb, float* __restrict__ out)
{
    cg::grid_group grid = cg::this_grid();
    __shared__ float ybuf[4 * CDIM];   // 16 KB; reused: P2 q0full, P3 merge, P5/P6 staging
    __shared__ float ps[4];
    __shared__ float red[16];
    int tid = threadIdx.x, lane = tid & 63, wave = tid >> 6;
    int blk = blockIdx.x;

    // ---- P1: q0 partials (blocks 0..63) + zero out (block 64) ----
    if (blk < 64) {
        if (tid < 256) {
            int ic = blk >> 2, jc = blk & 3;       // 16 i-chunks of 64, 4 j-chunks of 256
            int j = jc * 256 + tid;
            int i0 = ic * 64;
            float acc = 0.f;
            for (int i = 0; i < 64; ++i)
                acc += t[i0 + i] * Wqkv[(size_t)(i0 + i) * TC + j];
            wsb[F_Q0P + ic * CDIM + j] = acc;
        }
    } else if (blk == 64) {
#pragma unroll
        for (int r = 0; r < 8; ++r) out[r * 1024 + tid] = 0.f;
    }
    grid.sync();

    // ---- P2: q0full in LDS, then Ws[h][c] (256 blocks x 16 waves = 4096 dots) ----
    if (tid < 256) {
        float4 q = *(const float4*)&bqkv[tid * 4];
#pragma unroll
        for (int ic = 0; ic < 16; ++ic) {
            float4 p = *(const float4*)&wsb[F_Q0P + ic * CDIM + tid * 4];
            q.x += p.x; q.y += p.y; q.z += p.z; q.w += p.w;
        }
        *(float4*)&ybuf[tid * 4] = q;
    }
    __syncthreads();
    {
        int c = blk * 4 + (wave >> 2), h = wave & 3;
        int d0 = h * 256 + lane * 4;
        float4 wv = *(const float4*)&Wqkv[(size_t)c * TC + CDIM + d0];
        float4 qv = *(const float4*)&ybuf[d0];
        float a = wv.x * qv.x + wv.y * qv.y + wv.z * qv.z + wv.w * qv.w;
        for (int off = 32; off > 0; off >>= 1) a += __shfl_down(a, off);
        if (lane == 0) wsb[F_WS + h * CDIM + c] = a;
    }
    grid.sync();

    // ---- P3: X scan in TWO head-pair passes (keeps live VGPRs ~95 < 128 cap) ----
    {
        int b = blk >> 5, ch = blk & 31;
        const float* base = x + ((size_t)b * NIN + ch * 64 + wave * 4) * CDIM;
        __syncthreads();                      // ybuf done serving P2
        for (int idx = tid; idx < 4 * CDIM; idx += 1024) ybuf[idx] = 0.f;
        if (tid < 4) ps[tid] = 0.f;
        __syncthreads();

        for (int pass = 0; pass < 2; ++pass) {
            int h0 = pass * 2;
            float4 wsr[4][2];
#pragma unroll
            for (int k = 0; k < 4; ++k)
#pragma unroll
                for (int hh = 0; hh < 2; ++hh)
                    wsr[k][hh] = *(const float4*)&wsb[F_WS + (h0 + hh) * CDIM + k * 256 + lane * 4];
            float s0 = 0.f, s1 = 0.f;
            float4 y[2][4];
#pragma unroll
            for (int k = 0; k < 4; ++k) {
                y[0][k] = make_float4(0.f, 0.f, 0.f, 0.f);
                y[1][k] = make_float4(0.f, 0.f, 0.f, 0.f);
            }
#pragma unroll 2
            for (int i = 0; i < 4; ++i) {
                const float* row = base + (size_t)i * CDIM;
                float4 xv[4];
#pragma unroll
                for (int k = 0; k < 4; ++k) xv[k] = *(const float4*)&row[k * 256 + lane * 4];
                float a0 = 0.f, a1 = 0.f;
#pragma unroll
                for (int k = 0; k < 4; ++k) {
                    a0 += xv[k].x * wsr[k][0].x + xv[k].y * wsr[k][0].y +
                          xv[k].z * wsr[k][0].z + xv[k].w * wsr[k][0].w;
                    a1 += xv[k].x * wsr[k][1].x + xv[k].y * wsr[k][1].y +
                          xv[k].z * wsr[k][1].z + xv[k].w * wsr[k][1].w;
                }
                for (int off = 1; off < 64; off <<= 1) {
                    a0 += __shfl_xor(a0, off);
                    a1 += __shfl_xor(a1, off);
                }
                float e0 = __expf(a0 * 0.0625f);   // Dh=256 -> 1/16; +ck cancels in softmax
                float e1 = __expf(a1 * 0.0625f);
                s0 += e0; s1 += e1;
#pragma unroll
                for (int k = 0; k < 4; ++k) {
                    y[0][k].x += e0 * xv[k].x; y[0][k].y += e0 * xv[k].y;
                    y[0][k].z += e0 * xv[k].z; y[0][k].w += e0 * xv[k].w;
                    y[1][k].x += e1 * xv[k].x; y[1][k].y += e1 * xv[k].y;
                    y[1][k].z += e1 * xv[k].z; y[1][k].w += e1 * xv[k].w;
                }
            }
            // merge into permuted ybuf via LDS f32 atomics (2-way bank alias = free)
#pragma unroll
            for (int hh = 0; hh < 2; ++hh)
#pragma unroll
                for (int k = 0; k < 4; ++k) {
                    float* bp = &ybuf[(h0 + hh) * 1024 + k * 256];
                    atomicAdd(&bp[0 * 64 + lane], y[hh][k].x);
                    atomicAdd(&bp[1 * 64 + lane], y[hh][k].y);
                    atomicAdd(&bp[2 * 64 + lane], y[hh][k].z);
                    atomicAdd(&bp[3 * 64 + lane], y[hh][k].w);
                }
            if (lane == 0) { atomicAdd(&ps[h0], s0); atomicAdd(&ps[h0 + 1], s1); }
        }
        __syncthreads();
        for (int idx = tid; idx < 4 * CDIM; idx += 1024)
            wsb[F_PY + (size_t)blk * 4096 + idx] = ybuf[idx];
        if (tid < 4) wsb[F_PS + blk * 4 + tid] = ps[tid];
    }
    grid.sync();

    // ---- P4: combine 32 block-partials + class-token term -> ybar (128 roles) ----
    if (blk < 128) {
        int b = blk >> 4, h = (blk >> 2) & 3, kq = blk & 3;
        if (tid < 256) {
            float4 tv = *(const float4*)&t[tid * 4];
            float4 wsv = *(const float4*)&wsb[F_WS + h * CDIM + tid * 4];
            float p = tv.x * wsv.x + tv.y * wsv.y + tv.z * wsv.z + tv.w * wsv.w;
            for (int off = 1; off < 64; off <<= 1) p += __shfl_xor(p, off);
            if (lane == 0) red[wave] = p;
        }
        if (wave == 0) {
            float sv = (lane < 32) ? wsb[F_PS + (size_t)(b * 32 + lane) * 4 + h] : 0.f;
            for (int off = 32; off > 0; off >>= 1) sv += __shfl_down(sv, off);
            if (lane == 0) red[8] = sv;
        }
        __syncthreads();
        float sc0 = (red[0] + red[1] + red[2] + red[3]) * 0.0625f;
        float e0 = __expf(sc0);
        float S = red[8] + e0;
        if (tid < 256) {
            int pidx = h * 1024 + kq * 256 + tid;            // permuted slot
            int c = kq * 256 + (tid & 63) * 4 + (tid >> 6);  // natural column
            float acc = 0.f;
#pragma unroll 4
            for (int m = 0; m < 32; ++m)
                acc += wsb[F_PY + (size_t)(b * 32 + m) * 4096 + pidx];
            wsb[F_YB + (size_t)(b * 4 + h) * CDIM + c] = (acc + e0 * t[c]) / S;
        }
    }
    grid.sync();

    // ---- P5: ocp[q][b][cp] = ybar[b][h(cp)][q-slice] . Wqkv_V (128 roles) ----
    if (blk < 128) {
        int p = blk >> 4, q = blk & 15;       // p: cp-chunk of 128; q: c-chunk of 64
        int h = p >> 1;
        if (tid < 512) {
            int bb = tid >> 6, cc = tid & 63;
            ybuf[tid] = wsb[F_YB + (size_t)(bb * 4 + h) * CDIM + q * 64 + cc];
        }
        __syncthreads();
        int bb = tid >> 7, cl = tid & 127;
        int cp = p * 128 + cl;
        float acc = 0.f;
#pragma unroll 8
        for (int c = 0; c < 64; ++c)
            acc += ybuf[bb * 64 + c] * Wqkv[(size_t)(q * 64 + c) * TC + 2 * CDIM + cp];
        if (q == 0) acc += bqkv[2 * CDIM + cp];
        wsb[F_OCP + (size_t)(q * 8 + bb) * CDIM + cp] = acc;
    }
    grid.sync();

    // ---- P6: out[b][j] = oc[b] . Wv[:, j] + bv (128 roles, atomics into zeroed out) ----
    if (blk < 128) {
        int jp = blk >> 4, cq = blk & 15;     // jp: j-chunk of 128; cq: c-chunk of 64
        if (tid < 512) {
            int bb = tid >> 6, cc = tid & 63;
            float sum = 0.f;
#pragma unroll
            for (int q = 0; q < 16; ++q)
                sum += wsb[F_OCP + (size_t)(q * 8 + bb) * CDIM + cq * 64 + cc];
            ybuf[tid] = sum;
        }
        __syncthreads();
        int bb = tid >> 7, jl = tid & 127;
        int j = jp * 128 + jl;
        float acc = 0.f;
#pragma unroll 8
        for (int c = 0; c < 64; ++c)
            acc += ybuf[bb * 64 + c] * Wv[(size_t)(cq * 64 + c) * CDIM + j];
        if (cq == 0) acc += bv[j];
        atomicAdd(&out[bb * CDIM + j], acc);
    }
}

// ================= fallback: R6 stream-ordered pipeline (179 us) =================
#define OFF_Q0P 0
#define OFF_WS  16384
#define OFF_PS2 20480
#define OFF_PY2 24576
#define OFF_YB2 4218880
#define OFF_OCP2 4251648

__global__ void k_q0(const float* __restrict__ t, const float* __restrict__ W,
                     float* __restrict__ wsb) {
    int ic = blockIdx.x >> 3, jc = blockIdx.x & 7;
    int j = jc * 128 + threadIdx.x;
    int i0 = ic * 64;
    float acc = 0.f;
    for (int i = 0; i < 64; ++i)
        acc += t[i0 + i] * W[(size_t)(i0 + i) * TC + j];
    wsb[OFF_Q0P + ic * CDIM + j] = acc;
}

__global__ void k_ws(const float* __restrict__ W, const float* __restrict__ bqkv,
                     float* __restrict__ wsb) {
    int wave = threadIdx.x >> 6, lane = threadIdx.x & 63;
    int c = blockIdx.x, h = wave;
    int d0 = h * 256 + lane * 4;
    float4 wv = *(const float4*)&W[(size_t)c * TC + CDIM + d0];
    float4 q = *(const float4*)&bqkv[d0];
#pragma unroll
    for (int ic = 0; ic < 16; ++ic) {
        float4 p = *(const float4*)&wsb[OFF_Q0P + ic * CDIM + d0];
        q.x += p.x; q.y += p.y; q.z += p.z; q.w += p.w;
    }
    float acc = wv.x * q.x + wv.y * q.y + wv.z * q.z + wv.w * q.w;
    for (int off = 32; off > 0; off >>= 1) acc += __shfl_down(acc, off);
    if (lane == 0) wsb[OFF_WS + h * CDIM + c] = acc;
}

__global__ __launch_bounds__(256) void k_pass1(const float* __restrict__ x,
                                               float* __restrict__ wsb) {
    int tid = threadIdx.x, lane = tid & 63, wave = tid >> 6;
    int b = blockIdx.x >> 7, blkc = blockIdx.x & 127;
    float4 wsr[4][4];
#pragma unroll
    for (int k = 0; k < 4; ++k)
#pragma unroll
        for (int h = 0; h < 4; ++h)
            wsr[k][h] = *(const float4*)&wsb[OFF_WS + h * CDIM + k * 256 + lane * 4];
    float s[4] = {0.f, 0.f, 0.f, 0.f};
    float4 y[4][4];
#pragma unroll
    for (int h = 0; h < 4; ++h)
#pragma unroll
        for (int k = 0; k < 4; ++k) y[h][k] = make_float4(0.f, 0.f, 0.f, 0.f);
    const float* base = x + ((size_t)b * NIN + blkc * 16 + wave * 4) * CDIM;
#pragma unroll 2
    for (int i = 0; i < 4; ++i) {
        const float* row = base + (size_t)i * CDIM;
        float4 xv[4];
#pragma unroll
        for (int k = 0; k < 4; ++k) xv[k] = *(const float4*)&row[k * 256 + lane * 4];
        float e[4];
#pragma unroll
        for (int h = 0; h < 4; ++h) {
            float a = 0.f;
#pragma unroll
            for (int k = 0; k < 4; ++k)
                a += xv[k].x * wsr[k][h].x + xv[k].y * wsr[k][h].y +
                     xv[k].z * wsr[k][h].z + xv[k].w * wsr[k][h].w;
            for (int off = 1; off < 64; off <<= 1) a += __shfl_xor(a, off);
            e[h] = __expf(a * 0.0625f);
        }
#pragma unroll
        for (int h = 0; h < 4; ++h) {
            float f = e[h];
            s[h] += f;
#pragma unroll
            for (int k = 0; k < 4; ++k) {
                y[h][k].x += f * xv[k].x; y[h][k].y += f * xv[k].y;
                y[h][k].z += f * xv[k].z; y[h][k].w += f * xv[k].w;
            }
        }
    }
    __shared__ float ss[4][4];
    __shared__ float ybuf[4][CDIM];
    if (lane == 0)
#pragma unroll
        for (int h = 0; h < 4; ++h) ss[wave][h] = s[h];
    for (int idx = tid; idx < 4 * CDIM; idx += 256) ((float*)ybuf)[idx] = 0.f;
    __syncthreads();
    for (int w = 0; w < 4; ++w) {
        if (wave == w) {
#pragma unroll
            for (int h = 0; h < 4; ++h)
#pragma unroll
                for (int k = 0; k < 4; ++k) {
                    float4* dst = (float4*)&ybuf[h][k * 256 + lane * 4];
                    float4 v = *dst;
                    v.x += y[h][k].x; v.y += y[h][k].y;
                    v.z += y[h][k].z; v.w += y[h][k].w;
                    *dst = v;
                }
        }
        __syncthreads();
    }
    int p = blockIdx.x;
    if (tid < 4)
        wsb[OFF_PS2 + p * 4 + tid] = ss[0][tid] + ss[1][tid] + ss[2][tid] + ss[3][tid];
    for (int idx = tid; idx < 4 * CDIM; idx += 256)
        wsb[OFF_PY2 + (size_t)p * 4096 + idx] = ((float*)ybuf)[idx];
}

__global__ void k_comb(const float* __restrict__ t, float* __restrict__ wsb) {
    int tid = threadIdx.x, lane = tid & 63, wv = tid >> 6;
    int blk = blockIdx.x;
    int b = blk >> 4, h = (blk >> 2) & 3, cq = blk & 3;
    __shared__ float red[4], redS[4];
    int c0 = tid * 4;
    float4 tv = *(const float4*)&t[c0];
    float4 wsv = *(const float4*)&wsb[OFF_WS + h * CDIM + c0];
    float p = tv.x * wsv.x + tv.y * wsv.y + tv.z * wsv.z + tv.w * wsv.w;
    for (int off = 1; off < 64; off <<= 1) p += __shfl_xor(p, off);
    if (lane == 0) red[wv] = p;
    float sv = (tid < 128) ? wsb[OFF_PS2 + (size_t)(b * 128 + tid) * 4 + h] : 0.f;
    for (int off = 1; off < 64; off <<= 1) sv += __shfl_xor(sv, off);
    if (lane == 0) redS[wv] = sv;
    __syncthreads();
    float sc0 = (red[0] + red[1] + red[2] + red[3]) * 0.0625f;
    float e0 = __expf(sc0);
    float S = redS[0] + redS[1] + redS[2] + redS[3] + e0;
    int c = cq * 256 + tid;
    float acc = e0 * t[c];
#pragma unroll 4
    for (int j = 0; j < 128; ++j)
        acc += wsb[OFF_PY2 + (size_t)(b * 128 + j) * 4096 + h * CDIM + c];
    wsb[OFF_YB2 + (size_t)(b * 4 + h) * CDIM + c] = acc / S;
}

__global__ void k_ocy(const float* __restrict__ W, const float* __restrict__ bqkv,
                      float* __restrict__ wsb, float* __restrict__ out) {
    out[blockIdx.x * 128 + threadIdx.x] = 0.f;
    int p = blockIdx.x >> 3, q = blockIdx.x & 7;
    int h = p >> 1;
    __shared__ float sL[1024];
    for (int bb = 0; bb < 8; ++bb)
        sL[bb * 128 + threadIdx.x] = wsb[OFF_YB2 + (size_t)(bb * 4 + h) * CDIM + q * 128 + threadIdx.x];
    __syncthreads();
    int cp = p * 128 + threadIdx.x;
    float acc[8] = {0.f, 0.f, 0.f, 0.f, 0.f, 0.f, 0.f, 0.f};
    for (int c = 0; c < 128; ++c) {
        float wv = W[(size_t)(q * 128 + c) * TC + 2 * CDIM + cp];
#pragma unroll
        for (int bb = 0; bb < 8; ++bb) acc[bb] += sL[bb * 128 + c] * wv;
    }
    if (q == 0) {
        float bias = bqkv[2 * CDIM + cp];
#pragma unroll
        for (int bb = 0; bb < 8; ++bb) acc[bb] += bias;
    }
#pragma unroll
    for (int bb = 0; bb < 8; ++bb)
        wsb[OFF_OCP2 + (size_t)(q * 8 + bb) * CDIM + cp] = acc[bb];
}

__global__ void k_out(const float* __restrict__ Wv, const float* __restrict__ bv,
                      const float* __restrict__ wsb, float* __restrict__ out) {
    int jp = blockIdx.x >> 3, cq = blockIdx.x & 7;
    __shared__ float ocL[1024];
    for (int bb = 0; bb < 8; ++bb) {
        float sum = 0.f;
#pragma unroll
        for (int q = 0; q < 8; ++q)
            sum += wsb[OFF_OCP2 + (size_t)(q * 8 + bb) * CDIM + cq * 128 + threadIdx.x];
        ocL[bb * 128 + threadIdx.x] = sum;
    }
    __syncthreads();
    int j = jp * 128 + threadIdx.x;
    float acc[8] = {0.f, 0.f, 0.f, 0.f, 0.f, 0.f, 0.f, 0.f};
    for (int c = 0; c < 128; ++c) {
        float wv = Wv[(size_t)(cq * 128 + c) * CDIM + j];
#pragma unroll
        for (int bb = 0; bb < 8; ++bb) acc[bb] += ocL[bb * 128 + c] * wv;
    }
    if (cq == 0) {
        float bias = bv[j];
#pragma unroll
        for (int bb = 0; bb < 8; ++bb) acc[bb] += bias;
    }
#pragma unroll
    for (int bb = 0; bb < 8; ++bb) atomicAdd(&out[bb * CDIM + j], acc[bb]);
}

extern "C" void kernel_launch(void* const* d_in, const int* in_sizes, int n_in,
                              void* d_out, int out_size, void* d_ws, size_t ws_size,
                              hipStream_t stream) {
    const float* x    = (const float*)d_in[0];   // [8,2048,1024]
    const float* t    = (const float*)d_in[1];   // [1,1,1024]
    const float* Wqkv = (const float*)d_in[2];   // [1024,3072]
    const float* bqkv = (const float*)d_in[3];   // [3072]
    const float* Wv   = (const float*)d_in[4];   // [1024,1024]
    const float* bv   = (const float*)d_in[5];   // [1024]
    float* wsb = (float*)d_ws;
    float* out = (float*)d_out;                  // [8,1024] fp32

    // Spill guard: host-side attribute query (no stream op; graph-capture safe).
    // R7 lesson: a spilling fused kernel is 2x WORSE than the 6-kernel pipeline.
    bool use_fused = false;
    hipFuncAttributes attr;
    if (hipFuncGetAttributes(&attr, (const void*)k_fused) == hipSuccess)
        use_fused = (attr.localSizeBytes == 0);

    if (use_fused) {
        void* args[] = {(void*)&x, (void*)&t, (void*)&Wqkv, (void*)&bqkv,
                        (void*)&Wv, (void*)&bv, (void*)&wsb, (void*)&out};
        hipError_t err = hipLaunchCooperativeKernel((void*)k_fused, dim3(256), dim3(1024),
                                                    args, 0, stream);
        if (err == hipSuccess) return;
    }
    // deterministic fallback: R6 stream-ordered pipeline (179 us measured)
    k_q0   <<<128,  128, 0, stream>>>(t, Wqkv, wsb);
    k_ws   <<<1024, 256, 0, stream>>>(Wqkv, bqkv, wsb);
    k_pass1<<<1024, 256, 0, stream>>>(x, wsb);
    k_comb <<<128,  256, 0, stream>>>(t, wsb);
    k_ocy  <<<64,   128, 0, stream>>>(Wqkv, bqkv, wsb, out);
    k_out  <<<64,   128, 0, stream>>>(Wv, bv, wsb, out);
}

// Round 9
// 222.789 us; speedup vs baseline: 2.2385x; 1.6465x over previous
//
#include <hip/hip_runtime.h>
#include <math.h>

#define CDIM 1024
#define TC   3072
#define NIN  2048   // input rows per batch (class token handled separately)

// workspace float offsets (every slot written before read; ctrs zeroed by k_q0)
#define F_Q0P 0           // 16*1024 q0 i-chunk partials
#define F_WS  16384       // 4*1024  [h][c]
#define F_PS  20480       // 512*4   per-block exp-sums
#define F_PY  24576       // 512*4096 per-block y partials, natural [h][c]
#define F_OCP 2121728     // 8(q)*8(b)*1024 oc partials
#define F_CTR 2187264     // 3 uint barrier counters

// ---- dispatch 1: q0 partials + zero d_out + zero barrier counters ----
__global__ __launch_bounds__(256) void k_q0(const float* __restrict__ t,
                                            const float* __restrict__ W,
                                            float* __restrict__ wsb,
                                            float* __restrict__ out) {
    int blk = blockIdx.x, tid = threadIdx.x;
    if (blk == 0 && tid < 3) ((unsigned int*)(wsb + F_CTR))[tid] = 0u;
    if (blk < 32) out[blk * 256 + tid] = 0.f;
    int ic = blk >> 2, jc = blk & 3;             // 16 i-chunks of 64, 4 j-chunks of 256
    int j = jc * 256 + tid;
    int i0 = ic * 64;
    float acc = 0.f;
    for (int i = 0; i < 64; ++i)
        acc += t[i0 + i] * W[(size_t)(i0 + i) * TC + j];
    wsb[F_Q0P + ic * CDIM + j] = acc;
}

// ---- dispatch 2: ws -> bar -> pass1 -> bar -> comb+ocy -> bar -> out ----
// 512 blocks x 256 thr: <=4 blocks/CU even at 256 VGPR -> all co-resident,
// spin barriers deadlock-free (capacity argument, not dispatch-order).
__global__ __launch_bounds__(256) void k_mega(
    const float* __restrict__ x, const float* __restrict__ t,
    const float* __restrict__ Wqkv, const float* __restrict__ bqkv,
    const float* __restrict__ Wv, const float* __restrict__ bv,
    float* __restrict__ wsb, float* __restrict__ out)
{
    __shared__ float ybuf[4 * CDIM];
    __shared__ float aux[96];
    int tid = threadIdx.x, lane = tid & 63, wave = tid >> 6;
    int blk = blockIdx.x;
    unsigned int* ctr = (unsigned int*)(wsb + F_CTR);

    // ---------- phase WS: Ws[h][c] = Wk[c,h-slice].(q0+bq); 2 columns/block ----------
    {
        int h = wave, d0 = h * 256 + lane * 4;
        float4 q = *(const float4*)&bqkv[d0];
#pragma unroll
        for (int ic = 0; ic < 16; ++ic) {
            float4 p = *(const float4*)&wsb[F_Q0P + ic * CDIM + d0];
            q.x += p.x; q.y += p.y; q.z += p.z; q.w += p.w;
        }
#pragma unroll
        for (int cc = 0; cc < 2; ++cc) {
            int c = blk * 2 + cc;
            float4 wv = *(const float4*)&Wqkv[(size_t)c * TC + CDIM + d0];
            float a = wv.x * q.x + wv.y * q.y + wv.z * q.z + wv.w * q.w;
            for (int off = 32; off > 0; off >>= 1) a += __shfl_down(a, off);
            if (lane == 0) wsb[F_WS + h * CDIM + c] = a;
        }
    }
    // barrier 0: all 512 arrive, all wait
    __syncthreads();
    if (tid == 0) {
        __threadfence();
        atomicAdd(&ctr[0], 1u);
        while (__hip_atomic_load(&ctr[0], __ATOMIC_RELAXED, __HIP_MEMORY_SCOPE_AGENT) < 512u)
            __builtin_amdgcn_s_sleep(2);
        __threadfence();
    }
    __syncthreads();

    // ---------- phase PASS1: X scan (R6-proven shape: wave owns 8 rows) ----------
    {
        float4 wsr[4][4];
#pragma unroll
        for (int k = 0; k < 4; ++k)
#pragma unroll
            for (int h = 0; h < 4; ++h)
                wsr[k][h] = *(const float4*)&wsb[F_WS + h * CDIM + k * 256 + lane * 4];
        float s[4] = {0.f, 0.f, 0.f, 0.f};
        float4 y[4][4];
#pragma unroll
        for (int h = 0; h < 4; ++h)
#pragma unroll
            for (int k = 0; k < 4; ++k) y[h][k] = make_float4(0.f, 0.f, 0.f, 0.f);
        int b = blk >> 6, ch = blk & 63;
        const float* base = x + ((size_t)b * NIN + ch * 32 + wave * 8) * CDIM;
#pragma unroll 2
        for (int i = 0; i < 8; ++i) {
            const float* row = base + (size_t)i * CDIM;
            float4 xv[4];
#pragma unroll
            for (int k = 0; k < 4; ++k) xv[k] = *(const float4*)&row[k * 256 + lane * 4];
            float e[4];
#pragma unroll
            for (int h = 0; h < 4; ++h) {
                float a = 0.f;
#pragma unroll
                for (int k = 0; k < 4; ++k)
                    a += xv[k].x * wsr[k][h].x + xv[k].y * wsr[k][h].y +
                         xv[k].z * wsr[k][h].z + xv[k].w * wsr[k][h].w;
                for (int off = 1; off < 64; off <<= 1) a += __shfl_xor(a, off);
                e[h] = __expf(a * 0.0625f);   // Dh=256 -> 1/16; +ck cancels in softmax
            }
#pragma unroll
            for (int h = 0; h < 4; ++h) {
                float f = e[h];
                s[h] += f;
#pragma unroll
                for (int k = 0; k < 4; ++k) {
                    y[h][k].x += f * xv[k].x; y[h][k].y += f * xv[k].y;
                    y[h][k].z += f * xv[k].z; y[h][k].w += f * xv[k].w;
                }
            }
        }
        // sequential 4-wave merge through LDS (R6-proven)
        if (lane == 0)
#pragma unroll
            for (int h = 0; h < 4; ++h) aux[wave * 4 + h] = s[h];
        for (int idx = tid; idx < 4 * CDIM; idx += 256) ybuf[idx] = 0.f;
        __syncthreads();
        for (int w = 0; w < 4; ++w) {
            if (wave == w) {
#pragma unroll
                for (int h = 0; h < 4; ++h)
#pragma unroll
                    for (int k = 0; k < 4; ++k) {
                        float4* dst = (float4*)&ybuf[h * CDIM + k * 256 + lane * 4];
                        float4 v = *dst;
                        v.x += y[h][k].x; v.y += y[h][k].y;
                        v.z += y[h][k].z; v.w += y[h][k].w;
                        *dst = v;
                    }
            }
            __syncthreads();
        }
        if (tid < 4)
            wsb[F_PS + blk * 4 + tid] = aux[tid] + aux[4 + tid] + aux[8 + tid] + aux[12 + tid];
        for (int idx = tid; idx < 4 * CDIM; idx += 256)
            wsb[F_PY + (size_t)blk * 4096 + idx] = ybuf[idx];
    }
    // barrier 1: all arrive; only combocy blocks (0..31) wait
    __syncthreads();
    if (tid == 0) {
        __threadfence();
        atomicAdd(&ctr[1], 1u);
        if (blk < 32) {
            while (__hip_atomic_load(&ctr[1], __ATOMIC_RELAXED, __HIP_MEMORY_SCOPE_AGENT) < 512u)
                __builtin_amdgcn_s_sleep(2);
            __threadfence();
        }
    }
    __syncthreads();

    // ---------- phase COMBOCY (blocks 0..31): ybar slice + V-projection partials ----------
    if (blk < 32) {
        int h = blk >> 3, q = blk & 7;
        // sc0 = (t . Ws_h)/16
        {
            float4 tv = *(const float4*)&t[tid * 4];
            float4 wsv = *(const float4*)&wsb[F_WS + h * CDIM + tid * 4];
            float p = tv.x * wsv.x + tv.y * wsv.y + tv.z * wsv.z + tv.w * wsv.w;
            for (int off = 1; off < 64; off <<= 1) p += __shfl_xor(p, off);
            if (lane == 0) aux[64 + wave] = p;
        }
        __syncthreads();
        float e0 = __expf((aux[64] + aux[65] + aux[66] + aux[67]) * 0.0625f);
        // S[b] = e0 + sum of 64 PS partials
        if (tid < 64) {
            int b = tid >> 3, g = tid & 7;
            float sv = 0.f;
#pragma unroll
            for (int i = 0; i < 8; ++i)
                sv += wsb[F_PS + (size_t)(b * 64 + g * 8 + i) * 4 + h];
            aux[tid] = sv;
        }
        __syncthreads();
        if (tid < 8) {
            float S = e0;
#pragma unroll
            for (int k = 0; k < 8; ++k) S += aux[tid * 8 + k];
            aux[64 + tid] = 1.f / S;
        }
        __syncthreads();
        // ybar[b][h][q*128+cc] slice -> LDS (uses first 1024 floats of ybuf)
        {
            int b = tid >> 5, cc0 = (tid & 31) * 4;
            const float* tp = &t[q * 128 + cc0];
            float4 acc = make_float4(e0 * tp[0], e0 * tp[1], e0 * tp[2], e0 * tp[3]);
#pragma unroll 4
            for (int m = 0; m < 64; ++m) {
                float4 p = *(const float4*)&wsb[F_PY + (size_t)(b * 64 + m) * 4096 + h * 1024 + q * 128 + cc0];
                acc.x += p.x; acc.y += p.y; acc.z += p.z; acc.w += p.w;
            }
            float si = aux[64 + b];
            ybuf[b * 128 + cc0]     = acc.x * si;
            ybuf[b * 128 + cc0 + 1] = acc.y * si;
            ybuf[b * 128 + cc0 + 2] = acc.z * si;
            ybuf[b * 128 + cc0 + 3] = acc.w * si;
        }
        __syncthreads();
        // ocp[q][b][cp] for cp in h's 256-range
        {
            int cp = h * 256 + tid;
            float acc8[8] = {0.f, 0.f, 0.f, 0.f, 0.f, 0.f, 0.f, 0.f};
            for (int cc = 0; cc < 128; ++cc) {
                float w = Wqkv[(size_t)(q * 128 + cc) * TC + 2 * CDIM + cp];
#pragma unroll
                for (int b = 0; b < 8; ++b) acc8[b] += ybuf[b * 128 + cc] * w;
            }
            if (q == 0) {
                float bias = bqkv[2 * CDIM + cp];
#pragma unroll
                for (int b = 0; b < 8; ++b) acc8[b] += bias;
            }
#pragma unroll
            for (int b = 0; b < 8; ++b)
                wsb[F_OCP + (size_t)(q * 8 + b) * CDIM + cp] = acc8[b];
        }
        // barrier 2 arrive (producers only)
        __syncthreads();
        if (tid == 0) { __threadfence(); atomicAdd(&ctr[2], 1u); }
        return;
    }

    // ---------- phase OUT (blocks 32..95): out[b][j] = oc[b].Wv[:,j] + bv ----------
    if (blk < 96) {
        if (tid == 0) {
            while (__hip_atomic_load(&ctr[2], __ATOMIC_RELAXED, __HIP_MEMORY_SCOPE_AGENT) < 32u)
                __builtin_amdgcn_s_sleep(2);
            __threadfence();
        }
        __syncthreads();
        int ob = blk - 32, jp = ob >> 3, cq = ob & 7;
        // stage oc[b][cq-slice] (sum 8 q-partials): 1024 slots, 4 per thread
#pragma unroll
        for (int r = 0; r < 4; ++r) {
            int idx = r * 256 + tid;
            int bb = idx >> 7, cc = idx & 127;
            float sum = 0.f;
#pragma unroll
            for (int q = 0; q < 8; ++q)
                sum += wsb[F_OCP + (size_t)(q * 8 + bb) * CDIM + cq * 128 + cc];
            ybuf[idx] = sum;
        }
        __syncthreads();
        if (tid < 128) {
            int j = jp * 128 + tid;
            float acc8[8] = {0.f, 0.f, 0.f, 0.f, 0.f, 0.f, 0.f, 0.f};
            for (int c = 0; c < 128; ++c) {
                float w = Wv[(size_t)(cq * 128 + c) * CDIM + j];
#pragma unroll
                for (int bb = 0; bb < 8; ++bb) acc8[bb] += ybuf[bb * 128 + c] * w;
            }
            if (cq == 0) {
                float bias = bv[j];
#pragma unroll
                for (int bb = 0; bb < 8; ++bb) acc8[bb] += bias;
            }
#pragma unroll
            for (int bb = 0; bb < 8; ++bb) atomicAdd(&out[bb * CDIM + j], acc8[bb]);
        }
    }
}

extern "C" void kernel_launch(void* const* d_in, const int* in_sizes, int n_in,
                              void* d_out, int out_size, void* d_ws, size_t ws_size,
                              hipStream_t stream) {
    const float* x    = (const float*)d_in[0];   // [8,2048,1024]
    const float* t    = (const float*)d_in[1];   // [1,1,1024]
    const float* Wqkv = (const float*)d_in[2];   // [1024,3072]
    const float* bqkv = (const float*)d_in[3];   // [3072]
    const float* Wv   = (const float*)d_in[4];   // [1024,1024]
    const float* bv   = (const float*)d_in[5];   // [1024]
    float* wsb = (float*)d_ws;
    float* out = (float*)d_out;                  // [8,1024] fp32

    k_q0  <<<64,  256, 0, stream>>>(t, Wqkv, wsb, out);
    k_mega<<<512, 256, 0, stream>>>(x, t, Wqkv, bqkv, Wv, bv, wsb, out);
}